// Round 7
// baseline (3178.110 us; speedup 1.0000x reference)
//
#include <hip/hip_runtime.h>
#include <hip/hip_cooperative_groups.h>

namespace cg = cooperative_groups;

#define EPS 1e-5f
#define SELU_L 1.0507009873554805f
#define SELU_A 1.6732632423543772f
#define SELU_LA (SELU_L * SELU_A)

typedef _Float16 half8 __attribute__((ext_vector_type(8)));
typedef _Float16 half4 __attribute__((ext_vector_type(4)));
typedef float floatx4 __attribute__((ext_vector_type(4)));

__device__ __forceinline__ float selu_f(float x) {
    return x > 0.f ? SELU_L * x : SELU_LA * (__expf(x) - 1.f);
}

// ------------- weight swizzle prep: A-operand fragment order, fp16, t-major -------------
// wb_h : [t=18][mi=4][L=64][j=8]  co = mi*16 + (L&15), ci = (t&1)*32 + (L>>4)*8 + j, s = t>>1
// wb_in: [mi=4][L=64][j=8]        k = (L>>4)*8+j -> s=k/3, ci=k%3 (k>=27 -> 0)
// wb_out:[t=18][L=64][j=8]        co = L&15 (valid <3), ci/s as wb_h
__global__ __launch_bounds__(256) void k_prep(
    const float* __restrict__ w_h, const float* __restrict__ w_in,
    const float* __restrict__ w_out, _Float16* __restrict__ wb_h,
    _Float16* __restrict__ wb_in, _Float16* __restrict__ wb_out)
{
    int i = blockIdx.x * 256 + threadIdx.x;
    if (i < 36864) {
        int t = i >> 11;
        int rem = i & 2047;
        int mi = rem >> 9;
        int L = (rem >> 3) & 63;
        int j = i & 7;
        int co = mi * 16 + (L & 15);
        int ci = ((t & 1) << 5) + ((L >> 4) << 3) + j;
        int s = t >> 1;
        wb_h[i] = (_Float16)w_h[(co * 64 + ci) * 9 + s];
    } else if (i < 36864 + 2048) {
        int e = i - 36864;
        int mi = e >> 9;
        int L = (e >> 3) & 63;
        int j = e & 7;
        int co = mi * 16 + (L & 15);
        int k = ((L >> 4) << 3) + j;
        _Float16 val = (_Float16)0.f;
        if (k < 27) {
            int s = k / 3, ci = k - s * 3;
            val = (_Float16)w_in[(co * 3 + ci) * 9 + s];
        }
        wb_in[e] = val;
    } else if (i < 36864 + 2048 + 9216) {
        int e = i - 36864 - 2048;
        int t = e >> 9;
        int L = (e >> 3) & 63;
        int j = e & 7;
        int co = L & 15;
        int ci = ((t & 1) << 5) + ((L >> 4) << 3) + j;
        int s = t >> 1;
        _Float16 val = (_Float16)0.f;
        if (co < 3) val = (_Float16)w_out[(co * 64 + ci) * 9 + s];
        wb_out[e] = val;
    }
}

// ---------------- persistent whole-network kernel ----------------
// tile id -> (bx, by, b); 1024 tiles per layer, stolen via per-layer atomic counter.
__device__ __forceinline__ void conv_in_tile(
    int tile, const float* __restrict__ X, const _Float16* __restrict__ wb,
    _Float16* __restrict__ dst, float* s_x /*3*18*18*/, const float* s_sc,
    const float* s_bs, int tid)
{
    const int w0 = (tile & 15) << 4, h0 = ((tile >> 4) & 15) << 4, b = tile >> 8;
    for (int idx = tid; idx < 3 * 324; idx += 256) {
        int ci = idx / 324, rem = idx - ci * 324;
        int r = rem / 18, c = rem - r * 18;
        int gh = h0 - 1 + r, gw = w0 - 1 + c;
        float val = 0.f;
        if ((unsigned)gh < 256u && (unsigned)gw < 256u)
            val = X[((b * 3 + ci) << 16) + (gh << 8) + gw];
        s_x[(ci * 18 + r) * 18 + c] = val;
    }
    __syncthreads();

    const int wv = tid >> 6, L = tid & 63, quad = L >> 4, l15 = L & 15;
    half8 a[4];
    #pragma unroll
    for (int mi = 0; mi < 4; ++mi)
        a[mi] = *(const half8*)(wb + (mi * 64 + L) * 8);

    floatx4 acc[4][4];
    #pragma unroll
    for (int mi = 0; mi < 4; ++mi)
        #pragma unroll
        for (int ni = 0; ni < 4; ++ni) acc[mi][ni] = (floatx4){0.f, 0.f, 0.f, 0.f};

    #pragma unroll
    for (int ni = 0; ni < 4; ++ni) {
        half8 bfr;
        #pragma unroll
        for (int j = 0; j < 8; ++j) {
            int k = quad * 8 + j;
            float xv = 0.f;
            if (k < 27) {
                int s = k / 3, ci = k - s * 3;
                int kh = s / 3, kw = s - kh * 3;
                xv = s_x[(ci * 18 + wv * 4 + ni + kh) * 18 + l15 + kw];
            }
            bfr[j] = (_Float16)xv;
        }
        #pragma unroll
        for (int mi = 0; mi < 4; ++mi)
            acc[mi][ni] = __builtin_amdgcn_mfma_f32_16x16x32_f16(a[mi], bfr, acc[mi][ni], 0, 0, 0);
    }

    _Float16* db = dst + ((size_t)b << 22);
    #pragma unroll
    for (int mi = 0; mi < 4; ++mi) {
        const int cob = mi * 16 + (quad << 2);
        floatx4 sc = *(const floatx4*)(&s_sc[cob]);
        floatx4 bs = *(const floatx4*)(&s_bs[cob]);
        #pragma unroll
        for (int ni = 0; ni < 4; ++ni) {
            half4 ov;
            #pragma unroll
            for (int r = 0; r < 4; ++r)
                ov[r] = (_Float16)selu_f(acc[mi][ni][r] * sc[r] + bs[r]);
            const int row = h0 + wv * 4 + ni, col = w0 + l15;
            *(half4*)(db + ((((row << 8) + col) << 6) + cob)) = ov;
        }
    }
}

__device__ __forceinline__ void hidden_tile(
    int tile, const _Float16* __restrict__ src, const _Float16* __restrict__ wb,
    _Float16* __restrict__ dst, _Float16* s_in /*324*72*/, const float* s_sc,
    const float* s_bs, int tid)
{
    const int w0 = (tile & 15) << 4, h0 = ((tile >> 4) & 15) << 4, b = tile >> 8;
    const _Float16* sb = src + ((size_t)b << 22);
    for (int idx = tid; idx < 2592; idx += 256) {
        int r = idx / 144, cpos = idx - r * 144;
        int col = cpos >> 3, sub = cpos & 7;
        int gh = h0 - 1 + r, gw = w0 - 1 + col;
        half8 val = {0, 0, 0, 0, 0, 0, 0, 0};
        if ((unsigned)gh < 256u && (unsigned)gw < 256u)
            val = *(const half8*)(sb + ((((gh << 8) + gw) << 6) + (sub << 3)));
        *(half8*)(&s_in[(r * 18 + col) * 72 + (sub << 3)]) = val;
    }
    __syncthreads();

    const int wv = tid >> 6, L = tid & 63, quad = L >> 4, l15 = L & 15;
    floatx4 acc[4][4];
    #pragma unroll
    for (int mi = 0; mi < 4; ++mi)
        #pragma unroll
        for (int ni = 0; ni < 4; ++ni) acc[mi][ni] = (floatx4){0.f, 0.f, 0.f, 0.f};

    #pragma unroll
    for (int t = 0; t < 18; ++t) {
        const int s = t >> 1, ci0 = (t & 1) << 5;
        const int kh = s / 3, kw = s - kh * 3;
        half8 a[4];
        #pragma unroll
        for (int mi = 0; mi < 4; ++mi)
            a[mi] = *(const half8*)(wb + (((t * 4 + mi) * 64 + L) << 3));
        #pragma unroll
        for (int ni = 0; ni < 4; ++ni) {
            const int row = wv * 4 + ni + kh, col = l15 + kw;
            half8 bfr = *(const half8*)(&s_in[(row * 18 + col) * 72 + ci0 + (quad << 3)]);
            #pragma unroll
            for (int mi = 0; mi < 4; ++mi)
                acc[mi][ni] = __builtin_amdgcn_mfma_f32_16x16x32_f16(a[mi], bfr, acc[mi][ni], 0, 0, 0);
        }
    }

    _Float16* db = dst + ((size_t)b << 22);
    #pragma unroll
    for (int mi = 0; mi < 4; ++mi) {
        const int cob = mi * 16 + (quad << 2);
        floatx4 sc = *(const floatx4*)(&s_sc[cob]);
        floatx4 bs = *(const floatx4*)(&s_bs[cob]);
        #pragma unroll
        for (int ni = 0; ni < 4; ++ni) {
            half4 ov;
            #pragma unroll
            for (int r = 0; r < 4; ++r)
                ov[r] = (_Float16)selu_f(acc[mi][ni][r] * sc[r] + bs[r]);
            const int row = h0 + wv * 4 + ni, col = w0 + l15;
            *(half4*)(db + ((((row << 8) + col) << 6) + cob)) = ov;
        }
    }
}

__device__ __forceinline__ void conv_out_tile(
    int tile, const _Float16* __restrict__ src, const _Float16* __restrict__ wb,
    const float* __restrict__ bconv, const float* __restrict__ g,
    const float* __restrict__ be, const float* __restrict__ bm,
    const float* __restrict__ bv, const float* __restrict__ X,
    float* __restrict__ out, _Float16* s_in, int tid)
{
    const int w0 = (tile & 15) << 4, h0 = ((tile >> 4) & 15) << 4, b = tile >> 8;
    const _Float16* sb = src + ((size_t)b << 22);
    for (int idx = tid; idx < 2592; idx += 256) {
        int r = idx / 144, cpos = idx - r * 144;
        int col = cpos >> 3, sub = cpos & 7;
        int gh = h0 - 1 + r, gw = w0 - 1 + col;
        half8 val = {0, 0, 0, 0, 0, 0, 0, 0};
        if ((unsigned)gh < 256u && (unsigned)gw < 256u)
            val = *(const half8*)(sb + ((((gh << 8) + gw) << 6) + (sub << 3)));
        *(half8*)(&s_in[(r * 18 + col) * 72 + (sub << 3)]) = val;
    }
    __syncthreads();

    const int wv = tid >> 6, L = tid & 63, quad = L >> 4, l15 = L & 15;
    floatx4 acc[4];
    #pragma unroll
    for (int ni = 0; ni < 4; ++ni) acc[ni] = (floatx4){0.f, 0.f, 0.f, 0.f};

    #pragma unroll
    for (int t = 0; t < 18; ++t) {
        const int s = t >> 1, ci0 = (t & 1) << 5;
        const int kh = s / 3, kw = s - kh * 3;
        half8 a = *(const half8*)(wb + ((t * 64 + L) << 3));
        #pragma unroll
        for (int ni = 0; ni < 4; ++ni) {
            const int row = wv * 4 + ni + kh, col = l15 + kw;
            half8 bfr = *(const half8*)(&s_in[(row * 18 + col) * 72 + ci0 + (quad << 3)]);
            acc[ni] = __builtin_amdgcn_mfma_f32_16x16x32_f16(a, bfr, acc[ni], 0, 0, 0);
        }
    }

    if (quad == 0) {
        float sc[3], bs[3];
        #pragma unroll
        for (int co = 0; co < 3; ++co) {
            sc[co] = g[co] * rsqrtf(bv[co] + EPS);
            bs[co] = (bconv[co] - bm[co]) * sc[co] + be[co];
        }
        #pragma unroll
        for (int ni = 0; ni < 4; ++ni) {
            const int h = h0 + wv * 4 + ni, wc = w0 + l15;
            #pragma unroll
            for (int co = 0; co < 3; ++co) {
                float val = selu_f(acc[ni][co] * sc[co] + bs[co]);
                const float* Xc = X + ((size_t)(b * 3 + co) << 16);
                float x = Xc[(h << 8) + wc];
                float res;
                if (x == 0.f) {
                    float lft = (wc > 0)   ? Xc[(h << 8) + wc - 1] : 0.f;
                    float rgt = (wc < 255) ? Xc[(h << 8) + wc + 1] : 0.f;
                    float top = (h > 0)    ? Xc[((h - 1) << 8) + wc] : 0.f;
                    float bot = (h < 255)  ? Xc[((h + 1) << 8) + wc] : 0.f;
                    float sm = lft + rgt + top + bot;
                    int cnt = (lft > 0.f) + (rgt > 0.f) + (top > 0.f) + (bot > 0.f);
                    res = cnt > 0 ? sm / (float)cnt : 0.f;
                } else {
                    res = x;
                }
                out[((b * 3 + co) << 16) + (h << 8) + wc] = val + res;
            }
        }
    }
}

__global__ __launch_bounds__(256, 3) void k_net(
    const float* __restrict__ X,
    const _Float16* __restrict__ wb_in, const _Float16* __restrict__ wb_h,
    const _Float16* __restrict__ wb_out,
    const float* b_in, const float* g_in, const float* be_in, const float* m_in, const float* v_in,
    const float* b_h,  const float* g_h,  const float* be_h,  const float* m_h,  const float* v_h,
    const float* b_o,  const float* g_o,  const float* be_o,  const float* m_o,  const float* v_o,
    _Float16* act0, _Float16* act1, float* __restrict__ out, int* __restrict__ ctr)
{
    __shared__ __align__(16) char smem[324 * 72 * 2];   // 46.7 KB union
    __shared__ float s_sc[64], s_bs[64];
    __shared__ int s_tile;
    cg::grid_group grid = cg::this_grid();
    const int tid = threadIdx.x;

    // ---- layer 0: conv_in ----
    if (tid < 64) {
        float sc = g_in[tid] * rsqrtf(v_in[tid] + EPS);
        s_sc[tid] = sc;
        s_bs[tid] = (b_in[tid] - m_in[tid]) * sc + be_in[tid];
    }
    __syncthreads();
    for (;;) {
        if (tid == 0) s_tile = atomicAdd(&ctr[0], 1);
        __syncthreads();
        int tile = s_tile;
        if (tile >= 1024) break;
        conv_in_tile(tile, X, wb_in, act0, (float*)smem, s_sc, s_bs, tid);
        __syncthreads();
    }
    grid.sync();

    // ---- 18 hidden layers ----
    if (tid < 64) {
        float sc = g_h[tid] * rsqrtf(v_h[tid] + EPS);
        s_sc[tid] = sc;
        s_bs[tid] = (b_h[tid] - m_h[tid]) * sc + be_h[tid];
    }
    __syncthreads();
    const _Float16* src = act0;
    _Float16* dst = act1;
    for (int l = 0; l < 18; ++l) {
        for (;;) {
            if (tid == 0) s_tile = atomicAdd(&ctr[1 + l], 1);
            __syncthreads();
            int tile = s_tile;
            if (tile >= 1024) break;
            hidden_tile(tile, src, wb_h, dst, (_Float16*)smem, s_sc, s_bs, tid);
            __syncthreads();
        }
        grid.sync();
        const _Float16* t = src; src = dst; dst = (_Float16*)t;
    }

    // ---- conv_out + residual ----
    for (;;) {
        if (tid == 0) s_tile = atomicAdd(&ctr[19], 1);
        __syncthreads();
        int tile = s_tile;
        if (tile >= 1024) break;
        conv_out_tile(tile, src, wb_out, b_o, g_o, be_o, m_o, v_o, X, out,
                      (_Float16*)smem, tid);
        __syncthreads();
    }
}

extern "C" void kernel_launch(void* const* d_in, const int* in_sizes, int n_in,
                              void* d_out, int out_size, void* d_ws, size_t ws_size,
                              hipStream_t stream) {
    (void)in_sizes; (void)n_in; (void)out_size; (void)ws_size;
    const float* X    = (const float*)d_in[0];
    const float* w_in = (const float*)d_in[1];
    const float* b_in = (const float*)d_in[2];
    const float* g_in = (const float*)d_in[3];
    const float* be_in= (const float*)d_in[4];
    const float* m_in = (const float*)d_in[5];
    const float* v_in = (const float*)d_in[6];
    const float* w_h  = (const float*)d_in[7];
    const float* b_h  = (const float*)d_in[8];
    const float* g_h  = (const float*)d_in[9];
    const float* be_h = (const float*)d_in[10];
    const float* m_h  = (const float*)d_in[11];
    const float* v_h  = (const float*)d_in[12];
    const float* w_o  = (const float*)d_in[13];
    const float* b_o  = (const float*)d_in[14];
    const float* g_o  = (const float*)d_in[15];
    const float* be_o = (const float*)d_in[16];
    const float* m_o  = (const float*)d_in[17];
    const float* v_o  = (const float*)d_in[18];
    float* out = (float*)d_out;

    // ws layout (fp16 elems): act0[1<<24] act1[1<<24] wb_h[36864] wb_in[2048] wb_out[9216] ctr[32 ints]
    _Float16* act0  = (_Float16*)d_ws;
    _Float16* act1  = act0 + ((size_t)1 << 24);
    _Float16* wb_h  = act1 + ((size_t)1 << 24);
    _Float16* wb_in = wb_h + 36864;
    _Float16* wb_out= wb_in + 2048;
    int* ctr = (int*)(wb_out + 9216);

    hipMemsetAsync(ctr, 0, 32 * sizeof(int), stream);
    k_prep<<<188, 256, 0, stream>>>(w_h, w_in, w_o, wb_h, wb_in, wb_out);

    int occ = 0;
    hipOccupancyMaxActiveBlocksPerMultiprocessor(&occ, k_net, 256, 0);
    if (occ < 1) occ = 1;
    if (occ > 4) occ = 4;
    dim3 grid(256 * occ), block(256);

    void* args[] = {
        (void*)&X, (void*)&wb_in, (void*)&wb_h, (void*)&wb_out,
        (void*)&b_in, (void*)&g_in, (void*)&be_in, (void*)&m_in, (void*)&v_in,
        (void*)&b_h,  (void*)&g_h,  (void*)&be_h,  (void*)&m_h,  (void*)&v_h,
        (void*)&b_o,  (void*)&g_o,  (void*)&be_o,  (void*)&m_o,  (void*)&v_o,
        (void*)&act0, (void*)&act1, (void*)&out, (void*)&ctr
    };
    hipLaunchCooperativeKernel((void*)k_net, grid, block, args, 0, stream);
}

// Round 8
// 715.062 us; speedup vs baseline: 4.4445x; 4.4445x over previous
//
#include <hip/hip_runtime.h>

#define EPS 1e-5f
#define SELU_L 1.0507009873554805f
#define SELU_A 1.6732632423543772f
#define SELU_LA (SELU_L * SELU_A)

typedef _Float16 half8 __attribute__((ext_vector_type(8)));
typedef _Float16 half4 __attribute__((ext_vector_type(4)));
typedef float floatx4 __attribute__((ext_vector_type(4)));

__device__ __forceinline__ float selu_f(float x) {
    return x > 0.f ? SELU_L * x : SELU_LA * (__expf(x) - 1.f);
}

// ------------- weight swizzle prep: A-operand fragment order, fp16, t-major -------------
// wb_h : [t=18][mi=4][L=64][j=8]  co = mi*16 + (L&15), ci = (t&1)*32 + (L>>4)*8 + j, s = t>>1
// wb_in: [mi=4][L=64][j=8]        k = (L>>4)*8+j -> s=k/3, ci=k%3 (k>=27 -> 0)
// wb_out:[t=18][L=64][j=8]        co = L&15 (valid <3), ci/s as wb_h
__global__ __launch_bounds__(256) void k_prep(
    const float* __restrict__ w_h, const float* __restrict__ w_in,
    const float* __restrict__ w_out, _Float16* __restrict__ wb_h,
    _Float16* __restrict__ wb_in, _Float16* __restrict__ wb_out)
{
    int i = blockIdx.x * 256 + threadIdx.x;
    if (i < 36864) {
        int t = i >> 11;
        int rem = i & 2047;
        int mi = rem >> 9;
        int L = (rem >> 3) & 63;
        int j = i & 7;
        int co = mi * 16 + (L & 15);
        int ci = ((t & 1) << 5) + ((L >> 4) << 3) + j;
        int s = t >> 1;
        wb_h[i] = (_Float16)w_h[(co * 64 + ci) * 9 + s];
    } else if (i < 36864 + 2048) {
        int e = i - 36864;
        int mi = e >> 9;
        int L = (e >> 3) & 63;
        int j = e & 7;
        int co = mi * 16 + (L & 15);
        int k = ((L >> 4) << 3) + j;
        _Float16 val = (_Float16)0.f;
        if (k < 27) {
            int s = k / 3, ci = k - s * 3;
            val = (_Float16)w_in[(co * 3 + ci) * 9 + s];
        }
        wb_in[e] = val;
    } else if (i < 36864 + 2048 + 9216) {
        int e = i - 36864 - 2048;
        int t = e >> 9;
        int L = (e >> 3) & 63;
        int j = e & 7;
        int co = L & 15;
        int ci = ((t & 1) << 5) + ((L >> 4) << 3) + j;
        int s = t >> 1;
        _Float16 val = (_Float16)0.f;
        if (co < 3) val = (_Float16)w_out[(co * 64 + ci) * 9 + s];
        wb_out[e] = val;
    }
}

// ------------- conv_in: 3 -> 64, BN, SELU, NHWC fp16 out (MFMA, K=32) -------------
__global__ __launch_bounds__(256) void k_conv_in_mfma(
    const float* __restrict__ X, const _Float16* __restrict__ wb,
    const float* __restrict__ bconv, const float* __restrict__ g,
    const float* __restrict__ be, const float* __restrict__ bm,
    const float* __restrict__ bv, _Float16* __restrict__ dst)
{
    __shared__ float s_x[3][18][18];
    __shared__ float s_sc[64], s_bs[64];
    const int tid = threadIdx.x;
    const int w0 = blockIdx.x * 16, h0 = blockIdx.y * 16, b = blockIdx.z;

    if (tid < 64) {
        float sc = g[tid] * rsqrtf(bv[tid] + EPS);
        s_sc[tid] = sc;
        s_bs[tid] = (bconv[tid] - bm[tid]) * sc + be[tid];
    }
    for (int idx = tid; idx < 3 * 324; idx += 256) {
        int ci = idx / 324, rem = idx - ci * 324;
        int r = rem / 18, c = rem - r * 18;
        int gh = h0 - 1 + r, gw = w0 - 1 + c;
        float val = 0.f;
        if ((unsigned)gh < 256u && (unsigned)gw < 256u)
            val = X[((b * 3 + ci) << 16) + (gh << 8) + gw];
        s_x[ci][r][c] = val;
    }
    __syncthreads();

    const int wv = tid >> 6, L = tid & 63, quad = L >> 4, l15 = L & 15;
    half8 a[4];
    #pragma unroll
    for (int mi = 0; mi < 4; ++mi)
        a[mi] = *(const half8*)(wb + (mi * 64 + L) * 8);

    floatx4 acc[4][4];
    #pragma unroll
    for (int mi = 0; mi < 4; ++mi)
        #pragma unroll
        for (int ni = 0; ni < 4; ++ni) acc[mi][ni] = (floatx4){0.f, 0.f, 0.f, 0.f};

    #pragma unroll
    for (int ni = 0; ni < 4; ++ni) {
        half8 bfr;
        #pragma unroll
        for (int j = 0; j < 8; ++j) {
            int k = quad * 8 + j;
            float xv = 0.f;
            if (k < 27) {
                int s = k / 3, ci = k - s * 3;
                int kh = s / 3, kw = s - kh * 3;
                xv = s_x[ci][wv * 4 + ni + kh][l15 + kw];
            }
            bfr[j] = (_Float16)xv;
        }
        #pragma unroll
        for (int mi = 0; mi < 4; ++mi)
            acc[mi][ni] = __builtin_amdgcn_mfma_f32_16x16x32_f16(a[mi], bfr, acc[mi][ni], 0, 0, 0);
    }

    _Float16* db = dst + ((size_t)b << 22);  // b*256*256*64
    #pragma unroll
    for (int mi = 0; mi < 4; ++mi) {
        const int cob = mi * 16 + (quad << 2);
        floatx4 sc = *(const floatx4*)(&s_sc[cob]);
        floatx4 bs = *(const floatx4*)(&s_bs[cob]);
        #pragma unroll
        for (int ni = 0; ni < 4; ++ni) {
            half4 ov;
            #pragma unroll
            for (int r = 0; r < 4; ++r)
                ov[r] = (_Float16)selu_f(acc[mi][ni][r] * sc[r] + bs[r]);
            const int row = h0 + wv * 4 + ni, col = w0 + l15;
            *(half4*)(db + ((((row << 8) + col) << 6) + cob)) = ov;
        }
    }
}

// ------------- hidden: 64 -> 64, BN, SELU (MFMA implicit GEMM, K=576) -------------
// Weights staged through LDS (2-t chunks, reg-prefetched): 73.7 KB/block L2 traffic
// instead of 295 KB. Act stride 68 (conflict-free) keeps total LDS 52.8 KB -> 3 blocks/CU.
__global__ __launch_bounds__(256, 3) void k_hidden_mfma(
    const _Float16* __restrict__ src, const _Float16* __restrict__ wb,
    const float* __restrict__ bconv, const float* __restrict__ g,
    const float* __restrict__ be, const float* __restrict__ bm,
    const float* __restrict__ bv, _Float16* __restrict__ dst)
{
    __shared__ _Float16 s_in[324 * 68];   // 44.1 KB: [px=r*18+col][64 ci + 4 pad]
    __shared__ _Float16 s_w[4096];        // 8 KB: 2-t weight chunk [dt][mi][L][j]
    __shared__ float s_sc[64], s_bs[64];
    const int tid = threadIdx.x;
    const int w0 = blockIdx.x * 16, h0 = blockIdx.y * 16, b = blockIdx.z;
    const _Float16* sb = src + ((size_t)b << 22);

    if (tid < 64) {
        float sc = g[tid] * rsqrtf(bv[tid] + EPS);
        s_sc[tid] = sc;
        s_bs[tid] = (bconv[tid] - bm[tid]) * sc + be[tid];
    }

    // issue first weight-chunk loads early (latency overlaps activation staging)
    half8 wreg0 = *(const half8*)(wb + (tid << 3));
    half8 wreg1 = *(const half8*)(wb + 2048 + (tid << 3));

    // stage 18x18x64 fp16 halo tile, 16B chunks, coalesced (NHWC)
    const bool interior = (h0 != 0) & (h0 != 240) & (w0 != 0) & (w0 != 240);
    if (interior) {
        const _Float16* sbase = sb + ((((h0 - 1) << 8) + (w0 - 1)) << 6);
        for (int idx = tid; idx < 2592; idx += 256) {
            int r = idx / 144, cpos = idx - r * 144;
            int col = cpos >> 3, sub = cpos & 7;
            half8 val = *(const half8*)(sbase + (((r << 8) + col) << 6) + (sub << 3));
            *(half8*)(&s_in[(r * 18 + col) * 68 + (sub << 3)]) = val;
        }
    } else {
        for (int idx = tid; idx < 2592; idx += 256) {
            int r = idx / 144, cpos = idx - r * 144;
            int col = cpos >> 3, sub = cpos & 7;
            int gh = h0 - 1 + r, gw = w0 - 1 + col;
            half8 val = {0, 0, 0, 0, 0, 0, 0, 0};
            if ((unsigned)gh < 256u && (unsigned)gw < 256u)
                val = *(const half8*)(sb + ((((gh << 8) + gw) << 6) + (sub << 3)));
            *(half8*)(&s_in[(r * 18 + col) * 68 + (sub << 3)]) = val;
        }
    }
    __syncthreads();   // acts staged; wreg0/1 also drained here

    const int wv = tid >> 6, L = tid & 63, quad = L >> 4, l15 = L & 15;
    floatx4 acc[4][4];
    #pragma unroll
    for (int mi = 0; mi < 4; ++mi)
        #pragma unroll
        for (int ni = 0; ni < 4; ++ni) acc[mi][ni] = (floatx4){0.f, 0.f, 0.f, 0.f};

    for (int c = 0; c < 9; ++c) {
        // publish chunk c (2 t's) to LDS
        *(half8*)(&s_w[tid << 3]) = wreg0;
        *(half8*)(&s_w[2048 + (tid << 3)]) = wreg1;
        __syncthreads();
        // prefetch chunk c+1 (in flight across the ~32-MFMA compute window)
        if (c < 8) {
            wreg0 = *(const half8*)(wb + ((c + 1) << 12) + (tid << 3));
            wreg1 = *(const half8*)(wb + ((c + 1) << 12) + 2048 + (tid << 3));
        }
        #pragma unroll
        for (int dt = 0; dt < 2; ++dt) {
            const int t = 2 * c + dt;
            const int s = t >> 1, ci0 = (t & 1) << 5;
            const int kh = s / 3, kw = s - kh * 3;
            half8 a[4];
            #pragma unroll
            for (int mi = 0; mi < 4; ++mi)
                a[mi] = *(const half8*)(&s_w[(dt << 11) + (((mi << 6) + L) << 3)]);
            #pragma unroll
            for (int ni = 0; ni < 4; ++ni) {
                const int row = wv * 4 + ni + kh, col = l15 + kw;
                half8 bfr = *(const half8*)(&s_in[(row * 18 + col) * 68 + ci0 + (quad << 3)]);
                #pragma unroll
                for (int mi = 0; mi < 4; ++mi)
                    acc[mi][ni] = __builtin_amdgcn_mfma_f32_16x16x32_f16(a[mi], bfr, acc[mi][ni], 0, 0, 0);
            }
        }
        __syncthreads();   // all waves done reading s_w before next publish
    }

    _Float16* db = dst + ((size_t)b << 22);
    #pragma unroll
    for (int mi = 0; mi < 4; ++mi) {
        const int cob = mi * 16 + (quad << 2);
        floatx4 sc = *(const floatx4*)(&s_sc[cob]);
        floatx4 bs = *(const floatx4*)(&s_bs[cob]);
        #pragma unroll
        for (int ni = 0; ni < 4; ++ni) {
            half4 ov;
            #pragma unroll
            for (int r = 0; r < 4; ++r)
                ov[r] = (_Float16)selu_f(acc[mi][ni][r] * sc[r] + bs[r]);
            const int row = h0 + wv * 4 + ni, col = w0 + l15;
            *(half4*)(db + ((((row << 8) + col) << 6) + cob)) = ov;
        }
    }
}

// ------------- conv_out: 64 -> 3, BN, SELU, + interpolate_zeros(X), fp32 out -------------
__global__ __launch_bounds__(256, 3) void k_conv_out_mfma(
    const _Float16* __restrict__ src, const _Float16* __restrict__ wb,
    const float* __restrict__ bconv, const float* __restrict__ g,
    const float* __restrict__ be, const float* __restrict__ bm,
    const float* __restrict__ bv, const float* __restrict__ X,
    float* __restrict__ out)
{
    __shared__ _Float16 s_in[324 * 68];
    const int tid = threadIdx.x;
    const int w0 = blockIdx.x * 16, h0 = blockIdx.y * 16, b = blockIdx.z;
    const _Float16* sb = src + ((size_t)b << 22);

    for (int idx = tid; idx < 2592; idx += 256) {
        int r = idx / 144, cpos = idx - r * 144;
        int col = cpos >> 3, sub = cpos & 7;
        int gh = h0 - 1 + r, gw = w0 - 1 + col;
        half8 val = {0, 0, 0, 0, 0, 0, 0, 0};
        if ((unsigned)gh < 256u && (unsigned)gw < 256u)
            val = *(const half8*)(sb + ((((gh << 8) + gw) << 6) + (sub << 3)));
        *(half8*)(&s_in[(r * 18 + col) * 68 + (sub << 3)]) = val;
    }
    __syncthreads();

    const int wv = tid >> 6, L = tid & 63, quad = L >> 4, l15 = L & 15;
    floatx4 acc[4];
    #pragma unroll
    for (int ni = 0; ni < 4; ++ni) acc[ni] = (floatx4){0.f, 0.f, 0.f, 0.f};

    #pragma unroll
    for (int t = 0; t < 18; ++t) {
        const int s = t >> 1, ci0 = (t & 1) << 5;
        const int kh = s / 3, kw = s - kh * 3;
        half8 a = *(const half8*)(wb + ((t * 64 + L) << 3));
        #pragma unroll
        for (int ni = 0; ni < 4; ++ni) {
            const int row = wv * 4 + ni + kh, col = l15 + kw;
            half8 bfr = *(const half8*)(&s_in[(row * 18 + col) * 68 + ci0 + (quad << 3)]);
            acc[ni] = __builtin_amdgcn_mfma_f32_16x16x32_f16(a, bfr, acc[ni], 0, 0, 0);
        }
    }

    if (quad == 0) {
        float sc[3], bs[3];
        #pragma unroll
        for (int co = 0; co < 3; ++co) {
            sc[co] = g[co] * rsqrtf(bv[co] + EPS);
            bs[co] = (bconv[co] - bm[co]) * sc[co] + be[co];
        }
        #pragma unroll
        for (int ni = 0; ni < 4; ++ni) {
            const int h = h0 + wv * 4 + ni, wc = w0 + l15;
            #pragma unroll
            for (int co = 0; co < 3; ++co) {
                float val = selu_f(acc[ni][co] * sc[co] + bs[co]);
                const float* Xc = X + ((size_t)(b * 3 + co) << 16);
                float x = Xc[(h << 8) + wc];
                float res;
                if (x == 0.f) {
                    float lft = (wc > 0)   ? Xc[(h << 8) + wc - 1] : 0.f;
                    float rgt = (wc < 255) ? Xc[(h << 8) + wc + 1] : 0.f;
                    float top = (h > 0)    ? Xc[((h - 1) << 8) + wc] : 0.f;
                    float bot = (h < 255)  ? Xc[((h + 1) << 8) + wc] : 0.f;
                    float sm = lft + rgt + top + bot;
                    int cnt = (lft > 0.f) + (rgt > 0.f) + (top > 0.f) + (bot > 0.f);
                    res = cnt > 0 ? sm / (float)cnt : 0.f;
                } else {
                    res = x;
                }
                out[((b * 3 + co) << 16) + (h << 8) + wc] = val + res;
            }
        }
    }
}

extern "C" void kernel_launch(void* const* d_in, const int* in_sizes, int n_in,
                              void* d_out, int out_size, void* d_ws, size_t ws_size,
                              hipStream_t stream) {
    (void)in_sizes; (void)n_in; (void)out_size; (void)ws_size;
    const float* X    = (const float*)d_in[0];
    const float* w_in = (const float*)d_in[1];
    const float* b_in = (const float*)d_in[2];
    const float* g_in = (const float*)d_in[3];
    const float* be_in= (const float*)d_in[4];
    const float* m_in = (const float*)d_in[5];
    const float* v_in = (const float*)d_in[6];
    const float* w_h  = (const float*)d_in[7];
    const float* b_h  = (const float*)d_in[8];
    const float* g_h  = (const float*)d_in[9];
    const float* be_h = (const float*)d_in[10];
    const float* m_h  = (const float*)d_in[11];
    const float* v_h  = (const float*)d_in[12];
    const float* w_o  = (const float*)d_in[13];
    const float* b_o  = (const float*)d_in[14];
    const float* g_o  = (const float*)d_in[15];
    const float* be_o = (const float*)d_in[16];
    const float* m_o  = (const float*)d_in[17];
    const float* v_o  = (const float*)d_in[18];
    float* out = (float*)d_out;

    // ws layout (fp16 elems): act0[1<<24] act1[1<<24] wb_h[36864] wb_in[2048] wb_out[9216]
    _Float16* act0  = (_Float16*)d_ws;
    _Float16* act1  = act0 + ((size_t)1 << 24);
    _Float16* wb_h  = act1 + ((size_t)1 << 24);
    _Float16* wb_in = wb_h + 36864;
    _Float16* wb_out= wb_in + 2048;

    dim3 grid(16, 16, 4), block(256);
    k_prep<<<188, 256, 0, stream>>>(w_h, w_in, w_o, wb_h, wb_in, wb_out);
    k_conv_in_mfma<<<grid, block, 0, stream>>>(X, wb_in, b_in, g_in, be_in, m_in, v_in, act0);
    _Float16* src = act0;
    _Float16* dst = act1;
    for (int i = 0; i < 18; ++i) {
        k_hidden_mfma<<<grid, block, 0, stream>>>(src, wb_h, b_h, g_h, be_h, m_h, v_h, dst);
        _Float16* t = src; src = dst; dst = t;
    }
    k_conv_out_mfma<<<grid, block, 0, stream>>>(src, wb_out, b_o, g_o, be_o, m_o, v_o, X, out);
}